// Round 10
// baseline (140.471 us; speedup 1.0000x reference)
//
#include <hip/hip_runtime.h>

#define THREADS 512
#define DIN 60
#define HN 256
#define DOUT 360

typedef __attribute__((ext_vector_type(8))) short short8;
typedef __attribute__((ext_vector_type(16))) float f32x16;
typedef __attribute__((ext_vector_type(4))) float f32x4;
typedef __attribute__((ext_vector_type(2))) float f32x2;
typedef __attribute__((ext_vector_type(4))) unsigned int u32x4;

// d_ws layout (bytes); total 231424 B
#define WS_CBF   0            // 2048 * 16 B = 32768  (centres bf16+fold slots, [row][pc], pc=c^(row&7))
#define WS_CN    32768        // 256 floats: m2ns2 = 2*sigma^2*log2e  (1024 B)
#define WS_W2    34816        // [kc 0..31][row 0..383] short8 = 196608 B (bf16, out-col-permuted)

__device__ __forceinline__ short bf16_bits(float f) {   // prep-side only
    union { float f; unsigned u; } v; v.f = f;
    unsigned r = (v.u + 0x7FFFu + ((v.u >> 16) & 1u)) >> 16;
    return (short)(unsigned short)r;
}

__device__ __forceinline__ unsigned pk_bf16(float a, float b) {
    unsigned r;
    asm("v_cvt_pk_bf16_f32 %0, %1, %2" : "=v"(r) : "v"(a), "v"(b));
    return r;   // low16 = bf16(a), high16 = bf16(b)
}

__device__ __forceinline__ void gload16(const void* g, void* lds) {
    __builtin_amdgcn_global_load_lds(
        (const __attribute__((address_space(1))) unsigned int*)(uintptr_t)g,
        (__attribute__((address_space(3))) unsigned int*)(unsigned int)(uintptr_t)lds,
        16, 0, 0);
}

// ---------------- prep: convert/permute constants into ws ----------------
__global__ void prep(const float* __restrict__ centres, const float* __restrict__ sigmas,
                     const float* __restrict__ W2, short* __restrict__ ws)
{
    int t = blockIdx.x * 256 + threadIdx.x;
    if (t < 12288) {
        // W2 frags: [kc 0..31][row 0..383] short8; k = kc*8..kc*8+7
        int kc = t / 384, row = t % 384;
        short8 v = {0,0,0,0,0,0,0,0};
        if (row < DOUT) {
            int rr = row / 12, jj = row % 12;
            int fcl = rr / 3, kk = rr % 3;
            int o = fcl * 36 + jj * 3 + kk;            // fold output col permutation
            const float* src = W2 + o * HN + kc * 8;
            #pragma unroll
            for (int i = 0; i < 8; ++i) v[i] = bf16_bits(src[i]);
        }
        *(short8*)(ws + (WS_W2 / 2) + t * 8) = v;
    } else if (t < 14336) {
        // centres bf16 + fold slots: [row 0..255][pc 0..7], pc = c ^ (row&7)
        // k<60: c_k ; k=60: -0.5*c2hi ; k=61: -0.5*c2lo ; k=62,63: -0.5
        int j = t - 12288;
        int row = j >> 3, p = j & 7;
        int c = p ^ (row & 7);
        short8 v = {0,0,0,0,0,0,0,0};
        const float* cr = centres + row * DIN;
        if (c < 7) {
            #pragma unroll
            for (int i = 0; i < 8; ++i) {
                int k = c * 8 + i;
                if (k < DIN) v[i] = bf16_bits(cr[k]);
            }
        } else {   // k = 56..63
            #pragma unroll
            for (int i = 0; i < 4; ++i) v[i] = bf16_bits(cr[56 + i]);
            float c2 = 0.f;
            #pragma unroll
            for (int d = 0; d < DIN; ++d) c2 = fmaf(cr[d], cr[d], c2);
            union { unsigned u; float f; } hb;
            hb.u = ((unsigned)(unsigned short)bf16_bits(c2)) << 16;   // c2hi as float (bf16-exact)
            float c2lo = c2 - hb.f;
            v[4] = bf16_bits(-0.5f * hb.f);      // exact (power-of-2 scale)
            v[5] = bf16_bits(-0.5f * c2lo);
            v[6] = bf16_bits(-0.5f);
            v[7] = bf16_bits(-0.5f);
        }
        *(short8*)(ws + (WS_CBF / 2) + j * 8) = v;
    } else if (t < 14592) {
        int i = t - 14336;
        float sg = sigmas[i];
        ((float*)ws)[WS_CN / 4 + i] = 2.f * sg * sg * 1.44269504088896340736f;  // m2ns2 >= 0
    }
}

// --- main: 256 blocks x 512 thr; full 360 cols/block; W2 frags from global (L2) ---
__global__ __launch_bounds__(THREADS, 2)
void rbf_main(const float* __restrict__ x, const short* __restrict__ ws,
              float* __restrict__ out)
{
    __shared__ short8 cbf[2048];                               // 32 KB centres(+fold)
    __shared__ __attribute__((aligned(16))) float nsl[HN];     // 1 KB m2ns2

    const int tid  = threadIdx.x;
    const int w    = tid >> 6;              // wave 0..7
    const int lane = tid & 63;
    const int l31  = lane & 31;
    const int hi   = lane >> 5;
    const short* wbase = ws + (WS_W2 / 2);

    // ---- stage cbf + nsl once ----
    #pragma unroll
    for (int i = 0; i < 4; ++i)
        gload16(ws + (WS_CBF / 2) + (i * THREADS + tid) * 8, (char*)cbf + (i * THREADS + tid) * 16);
    if (tid < 64)
        gload16(ws + (WS_CN / 2) + tid * 8, (char*)nsl + tid * 16);

    // ---- iter-0 x: lane (l31,hi) = row l31, k = kt*16 + hi*8 + (0..7) ----
    int rbase = blockIdx.x * 512 + w * 32;
    f32x4 xa[4][2];
    {
        const float* xr = x + (size_t)(rbase + l31) * DIN;
        #pragma unroll
        for (int kt = 0; kt < 4; ++kt) {
            int k0 = kt * 16 + hi * 8;
            xa[kt][0] = *(const f32x4*)(xr + k0);
            xa[kt][1] = (k0 + 4 < DIN) ? *(const f32x4*)(xr + k0 + 4) : (f32x4){0.f,0.f,0.f,0.f};
        }
    }
    // pack xb (with fold slots) ; x2 via shuffle pair
    short8 xb[4];
    {
        float p2 = 0.f;
        #pragma unroll
        for (int kt = 0; kt < 4; ++kt)
            #pragma unroll
            for (int h = 0; h < 2; ++h)
                #pragma unroll
                for (int i = 0; i < 4; ++i) p2 = fmaf(xa[kt][h][i], xa[kt][h][i], p2);
        float x2v = p2 + __shfl_xor(p2, 32);
        union { unsigned u; float f; } hb; hb.u = pk_bf16(x2v, 0.f) << 16;  // bf16(x2) as float
        float x2lo = x2v - hb.f;
        #pragma unroll
        for (int kt = 0; kt < 4; ++kt) {
            union { u32x4 u; short8 s; } a;
            a.u[0] = pk_bf16(xa[kt][0][0], xa[kt][0][1]);
            a.u[1] = pk_bf16(xa[kt][0][2], xa[kt][0][3]);
            a.u[2] = pk_bf16(xa[kt][1][0], xa[kt][1][1]);
            a.u[3] = pk_bf16(xa[kt][1][2], xa[kt][1][3]);
            if (kt == 3) {   // hi lanes carry k=60..63 = {1, 1, x2hi, x2lo}
                a.u[2] = hi ? 0x3F803F80u : a.u[2];
                a.u[3] = hi ? pk_bf16(hb.f, x2lo) : a.u[3];
            }
            xb[kt] = a.s;
        }
    }

    __syncthreads();   // LDS resident; no barriers after this

    #pragma unroll
    for (int it = 0; it < 2; ++it) {
        // ---- issue next iter's x early ----
        if (it == 0) {
            const float* xr = x + (size_t)(rbase + 256 + l31) * DIN;
            #pragma unroll
            for (int kt = 0; kt < 4; ++kt) {
                int k0 = kt * 16 + hi * 8;
                xa[kt][0] = *(const f32x4*)(xr + k0);
                xa[kt][1] = (k0 + 4 < DIN) ? *(const f32x4*)(xr + k0 + 4) : (f32x4){0.f,0.f,0.f,0.f};
            }
        }

        // ---- GEMM1 (A=centres+fold, B=x+fold) + phi, two halves of 128 h ----
        unsigned pw[32][2];   // pw[b][p] = phi[h=8b+4hi+2p], [+1]   (row l31)
        #pragma unroll
        for (int h2 = 0; h2 < 2; ++h2) {
            f32x16 a1[4];
            #pragma unroll
            for (int nt = 0; nt < 4; ++nt) a1[nt] = (f32x16){};
            __builtin_amdgcn_s_setprio(1);
            #pragma unroll
            for (int nt = 0; nt < 4; ++nt) {
                int row = (h2 * 4 + nt) * 32 + l31;
                #pragma unroll
                for (int kt = 0; kt < 4; ++kt) {
                    short8 cf = cbf[row * 8 + ((kt * 2 + hi) ^ (row & 7))];
                    a1[nt] = __builtin_amdgcn_mfma_f32_32x32x16_bf16(cf, xb[kt], a1[nt], 0, 0, 0);
                }
            }
            __builtin_amdgcn_s_setprio(0);
            // phi = exp2(min(m2ns2 * S, 0)):  S = xc - (c2+x2)/2 <= 0
            #pragma unroll
            for (int nt = 0; nt < 4; ++nt) {
                int ntg = h2 * 4 + nt;
                #pragma unroll
                for (int q = 0; q < 4; ++q) {
                    f32x4 ns4 = *(const f32x4*)(nsl + ntg * 32 + 8 * q + 4 * hi);
                    float ph[4];
                    #pragma unroll
                    for (int j = 0; j < 4; ++j)
                        ph[j] = exp2f(fminf(ns4[j] * a1[nt][4 * q + j], 0.f));
                    pw[ntg * 4 + q][0] = pk_bf16(ph[0], ph[1]);
                    pw[ntg * 4 + q][1] = pk_bf16(ph[2], ph[3]);
                }
            }
        }

        // ---- convert next x now (xa dies before GEMM2) ----
        short8 xbn[4];
        if (it == 0) {
            float q2 = 0.f;
            #pragma unroll
            for (int kt = 0; kt < 4; ++kt)
                #pragma unroll
                for (int h = 0; h < 2; ++h)
                    #pragma unroll
                    for (int i = 0; i < 4; ++i) q2 = fmaf(xa[kt][h][i], xa[kt][h][i], q2);
            float x2n = q2 + __shfl_xor(q2, 32);
            union { unsigned u; float f; } hb; hb.u = pk_bf16(x2n, 0.f) << 16;
            float x2lo = x2n - hb.f;
            #pragma unroll
            for (int kt = 0; kt < 4; ++kt) {
                union { u32x4 u; short8 s; } a;
                a.u[0] = pk_bf16(xa[kt][0][0], xa[kt][0][1]);
                a.u[1] = pk_bf16(xa[kt][0][2], xa[kt][0][3]);
                a.u[2] = pk_bf16(xa[kt][1][0], xa[kt][1][1]);
                a.u[3] = pk_bf16(xa[kt][1][2], xa[kt][1][3]);
                if (kt == 3) {
                    a.u[2] = hi ? 0x3F803F80u : a.u[2];
                    a.u[3] = hi ? pk_bf16(hb.f, x2lo) : a.u[3];
                }
                xbn[kt] = a.s;
            }
        }

        // ---- GEMM2: A=W2 frags from GLOBAL (L2-hot, dbuf), B=phi (shuffle). 2 passes x 6 nt ----
        #pragma unroll
        for (int pass = 0; pass < 2; ++pass) {
            f32x16 a2[6];
            #pragma unroll
            for (int nt = 0; nt < 6; ++nt) a2[nt] = (f32x16){};
            short8 gf[2][6];
            #pragma unroll
            for (int nt = 0; nt < 6; ++nt)     // preload kt=0  (kc = hi)
                gf[0][nt] = *(const short8*)(wbase + ((size_t)hi * 384 + pass * 192 + nt * 32 + l31) * 8);

            #pragma unroll
            for (int kt = 0; kt < 16; ++kt) {
                if (kt < 15) {                  // prefetch kt+1
                    #pragma unroll
                    for (int nt = 0; nt < 6; ++nt)
                        gf[(kt + 1) & 1][nt] = *(const short8*)(wbase +
                            ((size_t)((kt + 1) * 2 + hi) * 384 + pass * 192 + nt * 32 + l31) * 8);
                }
                const int b = kt * 2;
                int A0 = __shfl((int)pw[b][0],     l31);
                int A1 = __shfl((int)pw[b][1],     l31);
                int C0 = __shfl((int)pw[b + 1][0], l31);
                int C1 = __shfl((int)pw[b + 1][1], l31);
                int B0 = __shfl((int)pw[b][0],     l31 + 32);
                int B1 = __shfl((int)pw[b][1],     l31 + 32);
                int D0 = __shfl((int)pw[b + 1][0], l31 + 32);
                int D1 = __shfl((int)pw[b + 1][1], l31 + 32);
                union { u32x4 u; short8 s; } bf;
                bf.u[0] = (unsigned)(hi ? C0 : A0);
                bf.u[1] = (unsigned)(hi ? C1 : A1);
                bf.u[2] = (unsigned)(hi ? D0 : B0);
                bf.u[3] = (unsigned)(hi ? D1 : B1);

                __builtin_amdgcn_s_setprio(1);
                #pragma unroll
                for (int nt = 0; nt < 6; ++nt)
                    a2[nt] = __builtin_amdgcn_mfma_f32_32x32x16_bf16(gf[kt & 1][nt], bf.s, a2[nt], 0, 0, 0);
                __builtin_amdgcn_s_setprio(0);
            }

            // ---- stores (nontemporal): lane owns batch-row rbase+l31; 4 cols per reg-quad ----
            float* op = out + (size_t)(rbase + l31) * DOUT;
            #pragma unroll
            for (int nt = 0; nt < 6; ++nt) {
                #pragma unroll
                for (int q = 0; q < 4; ++q) {
                    int cb = pass * 192 + nt * 32 + q * 8;     // wave-uniform base
                    if (cb < DOUT) {
                        f32x4 v;
                        v[0] = a2[nt][4 * q + 0]; v[1] = a2[nt][4 * q + 1];
                        v[2] = a2[nt][4 * q + 2]; v[3] = a2[nt][4 * q + 3];
                        __builtin_nontemporal_store(v, (f32x4*)(op + cb + hi * 4));
                    }
                }
            }
        }

        if (it == 0) {
            #pragma unroll
            for (int kt = 0; kt < 4; ++kt) xb[kt] = xbn[kt];
        }
        rbase += 256;
    }
}

extern "C" void kernel_launch(void* const* d_in, const int* in_sizes, int n_in,
                              void* d_out, int out_size, void* d_ws, size_t ws_size,
                              hipStream_t stream) {
    const float* x       = (const float*)d_in[0];
    const float* centres = (const float*)d_in[1];
    const float* sigmas  = (const float*)d_in[2];
    const float* W2      = (const float*)d_in[3];
    float* out = (float*)d_out;
    short* ws  = (short*)d_ws;                  // needs 231424 B
    prep<<<dim3(57), dim3(256), 0, stream>>>(centres, sigmas, W2, ws);
    rbf_main<<<dim3(256), dim3(THREADS), 0, stream>>>(x, ws, out);
}

// Round 12
// 66.728 us; speedup vs baseline: 2.1051x; 2.1051x over previous
//
#include <hip/hip_runtime.h>

#define THREADS 512
#define DIN 60
#define HN 256
#define DOUT 360

typedef __attribute__((ext_vector_type(8))) short short8;
typedef __attribute__((ext_vector_type(16))) float f32x16;
typedef __attribute__((ext_vector_type(4))) float f32x4;
typedef __attribute__((ext_vector_type(2))) float f32x2;
typedef __attribute__((ext_vector_type(4))) unsigned int u32x4;

// d_ws layout (bytes); total 231424 B
#define WS_CBF   0            // 2048 * 16 B = 32768  (centres bf16 + fold slots, [row][pc], pc=c^(row&7))
#define WS_CN    32768        // 256 floats m2ns2 = 2*sigma^2*log2e (1024 B)
#define WS_W2    34816        // [row 0..383][pc 0..31] short8, pc=c^(row&31) = 196608 B

__device__ __forceinline__ short bf16_bits(float f) {   // prep-side only
    union { float f; unsigned u; } v; v.f = f;
    unsigned r = (v.u + 0x7FFFu + ((v.u >> 16) & 1u)) >> 16;
    return (short)(unsigned short)r;
}

__device__ __forceinline__ unsigned pk_bf16(float a, float b) {
    unsigned r;
    asm("v_cvt_pk_bf16_f32 %0, %1, %2" : "=v"(r) : "v"(a), "v"(b));
    return r;   // low16 = bf16(a), high16 = bf16(b)
}

__device__ __forceinline__ void gload16(const void* g, void* lds) {
    __builtin_amdgcn_global_load_lds(
        (const __attribute__((address_space(1))) unsigned int*)(uintptr_t)g,
        (__attribute__((address_space(3))) unsigned int*)(unsigned int)(uintptr_t)lds,
        16, 0, 0);
}

// ---------------- prep: convert/permute constants into ws ----------------
__global__ void prep(const float* __restrict__ centres, const float* __restrict__ sigmas,
                     const float* __restrict__ W2, short* __restrict__ ws)
{
    int t = blockIdx.x * 256 + threadIdx.x;
    if (t < 12288) {
        // W2: [row 0..383][pc 0..31] short8; pc = c ^ (row&31); k = c*8..c*8+7
        int row = t >> 5, pc = t & 31;
        int c = pc ^ (row & 31);
        short8 v = {0,0,0,0,0,0,0,0};
        if (row < DOUT) {
            int rr = row / 12, jj = row % 12;
            int fcl = rr / 3, kk = rr % 3;
            int o = fcl * 36 + jj * 3 + kk;            // fold output col permutation
            const float* src = W2 + o * HN + c * 8;
            #pragma unroll
            for (int i = 0; i < 8; ++i) v[i] = bf16_bits(src[i]);
        }
        *(short8*)(ws + (WS_W2 / 2) + t * 8) = v;
    } else if (t < 14336) {
        // centres bf16 + fold slots: [row][pc 0..7], pc = c ^ (row&7)
        // k<60: c_k ; k=60: -0.5*c2hi ; k=61: -0.5*c2lo ; k=62,63: -0.5
        int j = t - 12288;
        int row = j >> 3, p = j & 7;
        int c = p ^ (row & 7);
        short8 v = {0,0,0,0,0,0,0,0};
        const float* cr = centres + row * DIN;
        if (c < 7) {
            #pragma unroll
            for (int i = 0; i < 8; ++i) {
                int k = c * 8 + i;
                if (k < DIN) v[i] = bf16_bits(cr[k]);
            }
        } else {   // k = 56..63
            #pragma unroll
            for (int i = 0; i < 4; ++i) v[i] = bf16_bits(cr[56 + i]);
            float c2 = 0.f;
            #pragma unroll
            for (int d = 0; d < DIN; ++d) c2 = fmaf(cr[d], cr[d], c2);
            union { unsigned u; float f; } hb;
            hb.u = ((unsigned)(unsigned short)bf16_bits(c2)) << 16;
            float c2lo = c2 - hb.f;
            v[4] = bf16_bits(-0.5f * hb.f);
            v[5] = bf16_bits(-0.5f * c2lo);
            v[6] = bf16_bits(-0.5f);
            v[7] = bf16_bits(-0.5f);
        }
        *(short8*)(ws + (WS_CBF / 2) + j * 8) = v;
    } else if (t < 14592) {
        int i = t - 14336;
        float sg = sigmas[i];
        ((float*)ws)[WS_CN / 4 + i] = 2.f * sg * sg * 1.44269504088896340736f;  // m2ns2
    }
}

// ---- load one 32-row x tile into fold-packed bf16 B-fragments (r10-verified) ----
__device__ __forceinline__ void load_xtile(const float* __restrict__ x, int row0,
                                           int l31, int hi, short8 xb[4]) {
    const float* xr = x + (size_t)(row0 + l31) * DIN;
    f32x4 xa[4][2];
    #pragma unroll
    for (int kt = 0; kt < 4; ++kt) {
        int k0 = kt * 16 + hi * 8;
        xa[kt][0] = *(const f32x4*)(xr + k0);
        xa[kt][1] = (k0 + 4 < DIN) ? *(const f32x4*)(xr + k0 + 4) : (f32x4){0.f,0.f,0.f,0.f};
    }
    float p2 = 0.f;
    #pragma unroll
    for (int kt = 0; kt < 4; ++kt)
        #pragma unroll
        for (int h = 0; h < 2; ++h)
            #pragma unroll
            for (int i = 0; i < 4; ++i) p2 = fmaf(xa[kt][h][i], xa[kt][h][i], p2);
    float x2v = p2 + __shfl_xor(p2, 32);
    union { unsigned u; float f; } hb; hb.u = pk_bf16(x2v, 0.f) << 16;
    float x2lo = x2v - hb.f;
    #pragma unroll
    for (int kt = 0; kt < 4; ++kt) {
        union { u32x4 u; short8 s; } a;
        a.u[0] = pk_bf16(xa[kt][0][0], xa[kt][0][1]);
        a.u[1] = pk_bf16(xa[kt][0][2], xa[kt][0][3]);
        a.u[2] = pk_bf16(xa[kt][1][0], xa[kt][1][1]);
        a.u[3] = pk_bf16(xa[kt][1][2], xa[kt][1][3]);
        if (kt == 3) {   // hi lanes: k=60..63 B-side = {1, 1, x2hi, x2lo}
            a.u[2] = hi ? 0x3F803F80u : a.u[2];
            a.u[3] = hi ? pk_bf16(hb.f, x2lo) : a.u[3];
        }
        xb[kt] = a.s;
    }
}

// --- main: 256 blocks x 512 thr; paired tiles share LDS reads; permlane B-frags ---
__global__ __launch_bounds__(THREADS, 2)
void rbf_main(const float* __restrict__ x, const short* __restrict__ ws,
              float* __restrict__ out)
{
    __shared__ short8 w2h[6144];                               // 96 KB (this col-half)
    __shared__ short8 cbf[2048];                               // 32 KB centres+fold
    __shared__ __attribute__((aligned(16))) float nsl[HN];     // 1 KB m2ns2

    const int tid  = threadIdx.x;
    const int w    = tid >> 6;
    const int lane = tid & 63;
    const int l31  = lane & 31;
    const int hi   = lane >> 5;
    const int bid  = blockIdx.x;
    // XCD pair-swizzle: blocks bid and bid^8 share rows (same XCD), differ in col-half
    const int f     = (bid >> 3) & 1;
    const int sbase = (bid & 7) | ((bid >> 4) << 3);           // 0..127, bijective

    // ---- stage everything once (async DMA), one barrier total ----
    #pragma unroll
    for (int i = 0; i < 12; ++i)
        gload16(ws + (WS_W2 / 2) + ((size_t)f * 6144 + i * THREADS + tid) * 8,
                (char*)w2h + (i * THREADS + tid) * 16);
    #pragma unroll
    for (int i = 0; i < 4; ++i)
        gload16(ws + (WS_CBF / 2) + (i * THREADS + tid) * 8, (char*)cbf + (i * THREADS + tid) * 16);
    if (tid < 64)
        gload16(ws + (WS_CN / 2) + tid * 8, (char*)nsl + tid * 16);

    __syncthreads();

    for (int pit = 0; pit < 2; ++pit) {
        const int rb = sbase * 1024 + pit * 512 + w * 64;

        // ---- x fragments for both tiles ----
        short8 xb0[4], xb1[4];
        load_xtile(x, rb,      l31, hi, xb0);
        load_xtile(x, rb + 32, l31, hi, xb1);

        // ---- GEMM1 + phi: every cbf read feeds BOTH tiles ----
        unsigned pw0[32][2], pw1[32][2];
        #pragma unroll
        for (int h2 = 0; h2 < 2; ++h2) {
            f32x16 a0[4], a1v[4];
            #pragma unroll
            for (int nt = 0; nt < 4; ++nt) { a0[nt] = (f32x16){}; a1v[nt] = (f32x16){}; }
            __builtin_amdgcn_s_setprio(1);
            #pragma unroll
            for (int nt = 0; nt < 4; ++nt) {
                int row = (h2 * 4 + nt) * 32 + l31;
                #pragma unroll
                for (int kt = 0; kt < 4; ++kt) {
                    short8 cf = cbf[row * 8 + ((kt * 2 + hi) ^ (row & 7))];
                    a0[nt]  = __builtin_amdgcn_mfma_f32_32x32x16_bf16(cf, xb0[kt], a0[nt], 0, 0, 0);
                    a1v[nt] = __builtin_amdgcn_mfma_f32_32x32x16_bf16(cf, xb1[kt], a1v[nt], 0, 0, 0);
                }
            }
            __builtin_amdgcn_s_setprio(0);
            // phi = exp2(min(m2ns2 * S, 0)); ns4 shared across the pair
            #pragma unroll
            for (int nt = 0; nt < 4; ++nt) {
                int ntg = h2 * 4 + nt;
                #pragma unroll
                for (int q = 0; q < 4; ++q) {
                    f32x4 ns4 = *(const f32x4*)(nsl + ntg * 32 + 8 * q + 4 * hi);
                    float p0[4], p1[4];
                    #pragma unroll
                    for (int j = 0; j < 4; ++j) {
                        p0[j] = exp2f(fminf(ns4[j] * a0[nt][4 * q + j],  0.f));
                        p1[j] = exp2f(fminf(ns4[j] * a1v[nt][4 * q + j], 0.f));
                    }
                    pw0[ntg * 4 + q][0] = pk_bf16(p0[0], p0[1]);
                    pw0[ntg * 4 + q][1] = pk_bf16(p0[2], p0[3]);
                    pw1[ntg * 4 + q][0] = pk_bf16(p1[0], p1[1]);
                    pw1[ntg * 4 + q][1] = pk_bf16(p1[2], p1[3]);
                }
            }
        }

        // ---- GEMM2: every w2h read feeds both tiles; B-frags via permlane32_swap ----
        // v_permlane32_swap_b32 vdst, vsrc: vdst.row1 <-> vsrc.row0 (rows = 32-lane halves).
        // With vdst = pw[b] (low k-tile), vsrc = pw[b+1] (high k-tile):
        //   vdst' = u[0]/u[1] (lane-local k-half), vsrc' = u[2]/u[3] (partner-half).
        #pragma unroll
        for (int pass = 0; pass < 2; ++pass) {
            f32x16 c0[3], c1[3];
            #pragma unroll
            for (int nt = 0; nt < 3; ++nt) { c0[nt] = (f32x16){}; c1[nt] = (f32x16){}; }

            #pragma unroll
            for (int kt = 0; kt < 16; ++kt) {
                unsigned d00 = pw0[2 * kt][0], s00 = pw0[2 * kt + 1][0];
                unsigned d01 = pw0[2 * kt][1], s01 = pw0[2 * kt + 1][1];
                asm("v_permlane32_swap_b32 %0, %1" : "+v"(d00), "+v"(s00));
                asm("v_permlane32_swap_b32 %0, %1" : "+v"(d01), "+v"(s01));
                unsigned d10 = pw1[2 * kt][0], s10 = pw1[2 * kt + 1][0];
                unsigned d11 = pw1[2 * kt][1], s11 = pw1[2 * kt + 1][1];
                asm("v_permlane32_swap_b32 %0, %1" : "+v"(d10), "+v"(s10));
                asm("v_permlane32_swap_b32 %0, %1" : "+v"(d11), "+v"(s11));
                union { u32x4 u; short8 s; } b0, b1;
                b0.u[0] = d00; b0.u[1] = d01; b0.u[2] = s00; b0.u[3] = s01;
                b1.u[0] = d10; b1.u[1] = d11; b1.u[2] = s10; b1.u[3] = s11;

                __builtin_amdgcn_s_setprio(1);
                #pragma unroll
                for (int nt = 0; nt < 3; ++nt) {
                    int lrow = (pass * 3 + nt) * 32 + l31;
                    short8 wf = w2h[lrow * 32 + ((kt * 2 + hi) ^ l31)];
                    c0[nt] = __builtin_amdgcn_mfma_f32_32x32x16_bf16(wf, b0.s, c0[nt], 0, 0, 0);
                    c1[nt] = __builtin_amdgcn_mfma_f32_32x32x16_bf16(wf, b1.s, c1[nt], 0, 0, 0);
                }
                __builtin_amdgcn_s_setprio(0);
            }

            // ---- stores: 4 back-to-back f32x4 per (tile,nt) -> contiguous 128B/row ----
            #pragma unroll
            for (int t = 0; t < 2; ++t) {
                float* op = out + (size_t)(rb + t * 32 + l31) * DOUT + f * 192 + pass * 96;
                #pragma unroll
                for (int nt = 0; nt < 3; ++nt) {
                    const f32x16& cc = t ? c1[nt] : c0[nt];
                    #pragma unroll
                    for (int q = 0; q < 4; ++q) {
                        int col = f * 192 + pass * 96 + nt * 32 + q * 8 + hi * 4;
                        if (col < DOUT) {
                            f32x4 v;
                            v[0] = cc[4 * q + 0]; v[1] = cc[4 * q + 1];
                            v[2] = cc[4 * q + 2]; v[3] = cc[4 * q + 3];
                            *(f32x4*)(op + nt * 32 + q * 8 + hi * 4) = v;
                        }
                    }
                }
            }
        }
    }
}

extern "C" void kernel_launch(void* const* d_in, const int* in_sizes, int n_in,
                              void* d_out, int out_size, void* d_ws, size_t ws_size,
                              hipStream_t stream) {
    const float* x       = (const float*)d_in[0];
    const float* centres = (const float*)d_in[1];
    const float* sigmas  = (const float*)d_in[2];
    const float* W2      = (const float*)d_in[3];
    float* out = (float*)d_out;
    short* ws  = (short*)d_ws;                  // needs 231424 B
    prep<<<dim3(57), dim3(256), 0, stream>>>(centres, sigmas, W2, ws);
    rbf_main<<<dim3(256), dim3(THREADS), 0, stream>>>(x, ws, out);
}